// Round 2
// baseline (139.014 us; speedup 1.0000x reference)
//
#include <hip/hip_runtime.h>

// GraphRetrieval fused kernel, MI355X (gfx950).
// B=16384, K=8, D=128, C=128. All fp32; labels int32.
//
// Per sample b:
//   logits = g@W_pred + b_pred            -> softmax over C -> g_label
//   t      = g@W_adapter
//   scores[m] = t . concat(g, retr)[m]    (m = 0..8) -> softmax -> attn
//   out[c] = attn[0]*g_label[c] + sum_{k=0..7} attn[k]*[labels[k]==c]
//   (note the reference quirk: the scatter uses attn indices 0..K-1, so
//    attn[0] appears both as the g_label scale AND the label[0] add)

#define SB      32      // samples per block
#define THREADS 256

__global__ __launch_bounds__(THREADS)
void graph_retrieval_fused(const float* __restrict__ G,      // [B,128]
                           const float* __restrict__ R,      // [B,8,128]
                           const float* __restrict__ Wa,     // [128,128]
                           const float* __restrict__ Wp,     // [128,128]
                           const float* __restrict__ bp,     // [128]
                           const int*   __restrict__ labels, // [B,8]
                           float* __restrict__ out)          // [B,128]
{
    __shared__ float g_lds[SB * 128];       // [s][d], row-major
    __shared__ float logit_lds[SB * 132];   // padded rows (132f = 528B, 16B aligned)
    __shared__ float t_lds[SB * 128];       // [s][d]
    __shared__ float attn_lds[SB * 12];     // [s][m], m=0..8 (+pad)
    __shared__ float stat_m[SB], stat_iz[SB];
    __shared__ int   lab_lds[SB * 8];

    const int tid = threadIdx.x;
    const int b0  = blockIdx.x * SB;

    // ---------- Phase A: stage g tile + labels ----------
    {
        const float4* Gv  = (const float4*)(G + (size_t)b0 * 128);
        float4*       gl4 = (float4*)g_lds;
        #pragma unroll
        for (int j = 0; j < 4; ++j)
            gl4[j * 256 + tid] = Gv[j * 256 + tid];     // 1024 float4 total
        lab_lds[tid] = labels[b0 * 8 + tid];            // SB*8 == 256
    }
    __syncthreads();

    const int c     = tid & 127;   // column owned (both for t-dim and logit-dim)
    const int h     = tid >> 7;    // sample half: 0 or 1
    const int sbase = h * 16;

    // ---------- Phase B: dual GEMM (t = g@Wa, logits = g@Wp + b) ----------
    float t_acc[16], l_acc[16];
    {
        const float bias = bp[c];
        #pragma unroll
        for (int i = 0; i < 16; ++i) { t_acc[i] = 0.f; l_acc[i] = bias; }

        for (int d0 = 0; d0 < 128; d0 += 4) {
            const float wa0 = Wa[(d0 + 0) * 128 + c];
            const float wa1 = Wa[(d0 + 1) * 128 + c];
            const float wa2 = Wa[(d0 + 2) * 128 + c];
            const float wa3 = Wa[(d0 + 3) * 128 + c];
            const float wp0 = Wp[(d0 + 0) * 128 + c];
            const float wp1 = Wp[(d0 + 1) * 128 + c];
            const float wp2 = Wp[(d0 + 2) * 128 + c];
            const float wp3 = Wp[(d0 + 3) * 128 + c];
            #pragma unroll
            for (int i = 0; i < 16; ++i) {
                const float4 g4 = *(const float4*)&g_lds[(sbase + i) * 128 + d0];
                t_acc[i] += g4.x * wa0 + g4.y * wa1 + g4.z * wa2 + g4.w * wa3;
                l_acc[i] += g4.x * wp0 + g4.y * wp1 + g4.z * wp2 + g4.w * wp3;
            }
        }

        #pragma unroll
        for (int i = 0; i < 16; ++i) {
            t_lds[(sbase + i) * 128 + c]     = t_acc[i];
            logit_lds[(sbase + i) * 132 + c] = l_acc[i];
        }
    }
    __syncthreads();

    // ---------- Phase C: logit softmax stats (8 threads per sample) ----------
    {
        const int s = tid >> 3;         // 0..31
        const int p = tid & 7;          // 0..7
        const float* row = &logit_lds[s * 132 + p * 16];
        float mx = row[0];
        #pragma unroll
        for (int j = 1; j < 16; ++j) mx = fmaxf(mx, row[j]);
        #pragma unroll
        for (int off = 1; off < 8; off <<= 1)
            mx = fmaxf(mx, __shfl_xor(mx, off, 64));
        float sum = 0.f;
        #pragma unroll
        for (int j = 0; j < 16; ++j) sum += __expf(row[j] - mx);
        #pragma unroll
        for (int off = 1; off < 8; off <<= 1)
            sum += __shfl_xor(sum, off, 64);
        if (p == 0) { stat_m[s] = mx; stat_iz[s] = 1.f / sum; }
    }
    __syncthreads();

    // ---------- Phase D: scores + attention softmax (wave per sample) ----------
    {
        const int wv   = tid >> 6;      // 0..3
        const int lane = tid & 63;
        #pragma unroll
        for (int si = 0; si < 8; ++si) {
            const int s = wv * 8 + si;
            const float2 t2 = *(const float2*)&t_lds[s * 128 + 2 * lane];
            float sc[9];
            {
                const float2 g2 = *(const float2*)&g_lds[s * 128 + 2 * lane];
                sc[0] = t2.x * g2.x + t2.y * g2.y;
            }
            const float2* Rrow = (const float2*)(R + (size_t)(b0 + s) * 8 * 128);
            #pragma unroll
            for (int m = 1; m < 9; ++m) {
                const float2 hv = Rrow[(m - 1) * 64 + lane];
                sc[m] = t2.x * hv.x + t2.y * hv.y;
            }
            // batched 64-lane butterfly reduction of all 9 partials
            #pragma unroll
            for (int off = 32; off > 0; off >>= 1) {
                #pragma unroll
                for (int m = 0; m < 9; ++m)
                    sc[m] += __shfl_xor(sc[m], off, 64);
            }
            // softmax over 9 (every lane redundantly; static indices only)
            float mx = sc[0];
            #pragma unroll
            for (int m = 1; m < 9; ++m) mx = fmaxf(mx, sc[m]);
            float e[9], sum = 0.f;
            #pragma unroll
            for (int m = 0; m < 9; ++m) { e[m] = __expf(sc[m] - mx); sum += e[m]; }
            const float inv = 1.f / sum;
            if (lane == 0) {
                #pragma unroll
                for (int m = 0; m < 9; ++m) attn_lds[s * 12 + m] = e[m] * inv;
            }
        }
    }
    __syncthreads();

    // ---------- Phase E: epilogue ----------
    #pragma unroll
    for (int i = 0; i < 16; ++i) {
        const int s = sbase + i;
        const float gl  = __expf(l_acc[i] - stat_m[s]) * stat_iz[s];
        float val = attn_lds[s * 12 + 0] * gl;
        #pragma unroll
        for (int k = 0; k < 8; ++k)
            val += (lab_lds[s * 8 + k] == c) ? attn_lds[s * 12 + k] : 0.f;
        out[(size_t)(b0 + s) * 128 + c] = val;
    }
}

extern "C" void kernel_launch(void* const* d_in, const int* in_sizes, int n_in,
                              void* d_out, int out_size, void* d_ws, size_t ws_size,
                              hipStream_t stream) {
    const float* G      = (const float*)d_in[0];
    const float* R      = (const float*)d_in[1];
    const float* Wa     = (const float*)d_in[2];
    const float* Wp     = (const float*)d_in[3];
    const float* bpred  = (const float*)d_in[4];
    const int*   labels = (const int*)d_in[5];
    float*       o      = (float*)d_out;

    const int B = in_sizes[0] / 128;   // 16384
    dim3 grid(B / SB), block(THREADS);
    hipLaunchKernelGGL(graph_retrieval_fused, grid, block, 0, stream,
                       G, R, Wa, Wp, bpred, labels, o);
}

// Round 4
// 137.050 us; speedup vs baseline: 1.0143x; 1.0143x over previous
//
#include <hip/hip_runtime.h>

// GraphRetrieval fused kernel, MI355X (gfx950).
// B=16384, K=8, D=128, C=128. All fp32; labels int32.
//
// Per sample b:
//   logits = g@W_pred + b_pred            -> softmax over C -> g_label
//   t      = g@W_adapter
//   scores[m] = t . concat(g, retr)[m]    (m = 0..8) -> softmax -> attn
//   out[c] = attn[0]*g_label[c] + sum_{k=0..7} attn[k]*[labels[k]==c]
//   (reference quirk: scatter uses attn[0..K-1]; attn[8] only feeds the
//    softmax normalization)
//
// Round-3 structure: SB=8 (grid=2048 blocks -> 8 blocks/CU available),
// ~13 KB LDS, 3 barriers. Round-2 (SB=32, grid=512) measured 17% occupancy,
// latency-bound at 55 us.

#define SB      8       // samples per block
#define THREADS 256

__global__ __launch_bounds__(THREADS)
void graph_retrieval_fused(const float* __restrict__ G,      // [B,128]
                           const float* __restrict__ R,      // [B,8,128]
                           const float* __restrict__ Wa,     // [128,128]
                           const float* __restrict__ Wp,     // [128,128]
                           const float* __restrict__ bp,     // [128]
                           const int*   __restrict__ labels, // [B,8]
                           float* __restrict__ out)          // [B,128]
{
    __shared__ float g_lds[SB * 128];       // 4 KB   [s][d]
    __shared__ float t_lds[SB * 128];       // 4 KB   [s][d]
    __shared__ float logit_lds[SB * 132];   // 4.2 KB padded rows
    __shared__ float attn_lds[SB * 8];      // attn[s][0..7]
    __shared__ float stat_m[SB], stat_iz[SB];
    __shared__ int   lab_lds[SB * 8];

    const int tid = threadIdx.x;
    const int b0  = blockIdx.x * SB;

    // ---------- Phase A: stage g tile + labels ----------
    ((float4*)g_lds)[tid] = ((const float4*)(G + (size_t)b0 * 128))[tid]; // 256 f4
    if (tid < SB * 8) lab_lds[tid] = labels[b0 * 8 + tid];
    __syncthreads();

    const int c     = tid & 127;   // owned column (t-dim and logit-dim)
    const int h     = tid >> 7;    // sample half
    const int sbase = h * 4;

    // ---------- Phase B: dual GEMM (t = g@Wa, logits = g@Wp + b) ----------
    float t_acc[4], l_acc[4];
    {
        const float bias = bp[c];
        #pragma unroll
        for (int i = 0; i < 4; ++i) { t_acc[i] = 0.f; l_acc[i] = bias; }

        for (int d0 = 0; d0 < 128; d0 += 8) {
            float wa[8], wp8[8];
            #pragma unroll
            for (int j = 0; j < 8; ++j) {
                wa[j]  = Wa[(d0 + j) * 128 + c];   // coalesced across lanes
                wp8[j] = Wp[(d0 + j) * 128 + c];
            }
            #pragma unroll
            for (int i = 0; i < 4; ++i) {
                const float4 ga = *(const float4*)&g_lds[(sbase + i) * 128 + d0];
                const float4 gb = *(const float4*)&g_lds[(sbase + i) * 128 + d0 + 4];
                t_acc[i] += ga.x * wa[0] + ga.y * wa[1] + ga.z * wa[2] + ga.w * wa[3]
                          + gb.x * wa[4] + gb.y * wa[5] + gb.z * wa[6] + gb.w * wa[7];
                l_acc[i] += ga.x * wp8[0] + ga.y * wp8[1] + ga.z * wp8[2] + ga.w * wp8[3]
                          + gb.x * wp8[4] + gb.y * wp8[5] + gb.z * wp8[6] + gb.w * wp8[7];
            }
        }
        #pragma unroll
        for (int i = 0; i < 4; ++i) {
            t_lds[(sbase + i) * 128 + c]     = t_acc[i];
            logit_lds[(sbase + i) * 132 + c] = l_acc[i];
        }
    }
    __syncthreads();

    // ---------- Phase D': per-wave {logit stats + scores + attn} ----------
    // wave w owns samples 2w, 2w+1
    {
        const int wv   = tid >> 6;
        const int lane = tid & 63;
        const int s0   = wv * 2;

        // logit softmax stats, batched over the 2 samples
        const float2 e0 = *(const float2*)&logit_lds[s0 * 132 + 2 * lane];
        const float2 e1 = *(const float2*)&logit_lds[(s0 + 1) * 132 + 2 * lane];
        float m0 = fmaxf(e0.x, e0.y), m1 = fmaxf(e1.x, e1.y);
        #pragma unroll
        for (int off = 32; off > 0; off >>= 1) {
            m0 = fmaxf(m0, __shfl_xor(m0, off, 64));
            m1 = fmaxf(m1, __shfl_xor(m1, off, 64));
        }
        float z0 = __expf(e0.x - m0) + __expf(e0.y - m0);
        float z1 = __expf(e1.x - m1) + __expf(e1.y - m1);
        #pragma unroll
        for (int off = 32; off > 0; off >>= 1) {
            z0 += __shfl_xor(z0, off, 64);
            z1 += __shfl_xor(z1, off, 64);
        }
        if (lane == 0) {
            stat_m[s0]      = m0;  stat_iz[s0]      = 1.f / z0;
            stat_m[s0 + 1]  = m1;  stat_iz[s0 + 1]  = 1.f / z1;
        }

        // scores for both samples (load all rows first, then batched reduce)
        float scA[9], scB[9];
        {
            const float2 tA = *(const float2*)&t_lds[s0 * 128 + 2 * lane];
            const float2 tB = *(const float2*)&t_lds[(s0 + 1) * 128 + 2 * lane];
            const float2 gA = *(const float2*)&g_lds[s0 * 128 + 2 * lane];
            const float2 gB = *(const float2*)&g_lds[(s0 + 1) * 128 + 2 * lane];
            scA[0] = tA.x * gA.x + tA.y * gA.y;
            scB[0] = tB.x * gB.x + tB.y * gB.y;
            const float2* RrA = (const float2*)(R + (size_t)(b0 + s0) * 8 * 128);
            const float2* RrB = (const float2*)(R + (size_t)(b0 + s0 + 1) * 8 * 128);
            #pragma unroll
            for (int m = 1; m < 9; ++m) {
                const float2 ra = RrA[(m - 1) * 64 + lane];   // 512B/row, coalesced
                const float2 rb = RrB[(m - 1) * 64 + lane];
                scA[m] = tA.x * ra.x + tA.y * ra.y;
                scB[m] = tB.x * rb.x + tB.y * rb.y;
            }
        }
        #pragma unroll
        for (int off = 32; off > 0; off >>= 1) {
            #pragma unroll
            for (int m = 0; m < 9; ++m) {
                scA[m] += __shfl_xor(scA[m], off, 64);
                scB[m] += __shfl_xor(scB[m], off, 64);
            }
        }
        // softmax over 9 (redundant per lane; static indices only)
        float mxA = scA[0], mxB = scB[0];
        #pragma unroll
        for (int m = 1; m < 9; ++m) { mxA = fmaxf(mxA, scA[m]); mxB = fmaxf(mxB, scB[m]); }
        float eA[9], eB[9], sA = 0.f, sB = 0.f;
        #pragma unroll
        for (int m = 0; m < 9; ++m) {
            eA[m] = __expf(scA[m] - mxA); sA += eA[m];
            eB[m] = __expf(scB[m] - mxB); sB += eB[m];
        }
        const float iA = 1.f / sA, iB = 1.f / sB;
        if (lane == 0) {
            #pragma unroll
            for (int m = 0; m < 8; ++m) {     // attn[8] only feeds normalization
                attn_lds[s0 * 8 + m]       = eA[m] * iA;
                attn_lds[(s0 + 1) * 8 + m] = eB[m] * iB;
            }
        }
    }
    __syncthreads();

    // ---------- Phase E: epilogue ----------
    #pragma unroll
    for (int i = 0; i < 4; ++i) {
        const int s = sbase + i;
        const float gl = __expf(l_acc[i] - stat_m[s]) * stat_iz[s];
        float val = attn_lds[s * 8 + 0] * gl;
        #pragma unroll
        for (int k = 0; k < 8; ++k)
            val += (lab_lds[s * 8 + k] == c) ? attn_lds[s * 8 + k] : 0.f;
        out[(size_t)(b0 + s) * 128 + c] = val;
    }
}

extern "C" void kernel_launch(void* const* d_in, const int* in_sizes, int n_in,
                              void* d_out, int out_size, void* d_ws, size_t ws_size,
                              hipStream_t stream) {
    const float* G      = (const float*)d_in[0];
    const float* R      = (const float*)d_in[1];
    const float* Wa     = (const float*)d_in[2];
    const float* Wp     = (const float*)d_in[3];
    const float* bpred  = (const float*)d_in[4];
    const int*   labels = (const int*)d_in[5];
    float*       o      = (float*)d_out;

    const int B = in_sizes[0] / 128;   // 16384
    dim3 grid(B / SB), block(THREADS);
    hipLaunchKernelGGL(graph_retrieval_fused, grid, block, 0, stream,
                       G, R, Wa, Wp, bpred, labels, o);
}

// Round 5
// 135.962 us; speedup vs baseline: 1.0224x; 1.0080x over previous
//
#include <hip/hip_runtime.h>

// GraphRetrieval fused kernel, MI355X (gfx950).
// B=16384, K=8, D=128, C=128. All fp32; labels int32.
//
// Per sample b:
//   logits = g@W_pred + b_pred            -> softmax over C -> g_label
//   t      = g@W_adapter
//   scores[m] = t . concat(g, retr)[m]    (m = 0..8) -> softmax -> attn
//   out[c] = attn[0]*g_label[c] + sum_{k=0..7} attn[k]*[labels[k]==c]
//   (reference quirk: scatter uses attn[0..K-1]; attn[8] only feeds the
//    softmax normalization)
//
// Round-5: latency-chain fixes on the round-4 structure (57us, 41% occ,
// 50% VALUBusy -> latency-bound, not occupancy-bound):
//   * R rows prefetched into registers at kernel start (consumed in the
//     score phase thousands of cycles later; phase D has zero VMEM)
//   * W double-buffered in registers (prefetch rows d0+8.. while FMA-ing
//     rows d0..) so 16 loads are always in flight under the FMA block

#define SB      8       // samples per block
#define THREADS 256

__global__ __launch_bounds__(THREADS, 4)
void graph_retrieval_fused(const float* __restrict__ G,      // [B,128]
                           const float* __restrict__ R,      // [B,8,128]
                           const float* __restrict__ Wa,     // [128,128]
                           const float* __restrict__ Wp,     // [128,128]
                           const float* __restrict__ bp,     // [128]
                           const int*   __restrict__ labels, // [B,8]
                           float* __restrict__ out)          // [B,128]
{
    __shared__ float g_lds[SB * 128];       // 4 KB   [s][d]
    __shared__ float t_lds[SB * 128];       // 4 KB   [s][d]
    __shared__ float logit_lds[SB * 132];   // 4.2 KB padded rows
    __shared__ float attn_lds[SB * 8];      // attn[s][0..7]
    __shared__ float stat_m[SB], stat_iz[SB];
    __shared__ int   lab_lds[SB * 8];

    const int tid  = threadIdx.x;
    const int b0   = blockIdx.x * SB;
    const int wv   = tid >> 6;
    const int lane = tid & 63;
    const int s0   = wv * 2;       // wave owns samples s0, s0+1 in phase D

    // ---------- R prefetch: issue the HBM stream FIRST ----------
    float2 rA[8], rB[8];
    {
        const float2* RrA = (const float2*)(R + (size_t)(b0 + s0) * 1024);
        const float2* RrB = RrA + 512;
        #pragma unroll
        for (int m = 0; m < 8; ++m) {
            rA[m] = RrA[m * 64 + lane];    // 512B/row, coalesced
            rB[m] = RrB[m * 64 + lane];
        }
    }

    // ---------- Phase A: stage g tile + labels ----------
    ((float4*)g_lds)[tid] = ((const float4*)(G + (size_t)b0 * 128))[tid]; // 256 f4
    if (tid < SB * 8) lab_lds[tid] = labels[b0 * 8 + tid];
    __syncthreads();

    const int c     = tid & 127;   // owned column (t-dim and logit-dim)
    const int h     = tid >> 7;    // sample half
    const int sbase = h * 4;

    // ---------- Phase B: dual GEMM, W double-buffered in registers ----------
    float t_acc[4], l_acc[4];
    {
        const float bias = bp[c];
        #pragma unroll
        for (int i = 0; i < 4; ++i) { t_acc[i] = 0.f; l_acc[i] = bias; }

        float waA[8], wpA[8], waB[8], wpB[8];
        #pragma unroll
        for (int j = 0; j < 8; ++j) {          // preload rows 0..7
            waA[j] = Wa[j * 128 + c];
            wpA[j] = Wp[j * 128 + c];
        }

        #pragma unroll
        for (int d0 = 0; d0 < 128; d0 += 16) {
            #pragma unroll
            for (int j = 0; j < 8; ++j) {      // prefetch rows d0+8..d0+15
                waB[j] = Wa[(d0 + 8 + j) * 128 + c];
                wpB[j] = Wp[(d0 + 8 + j) * 128 + c];
            }
            #pragma unroll
            for (int i = 0; i < 4; ++i) {      // FMA rows d0..d0+7 (buffer A)
                const float4 ga = *(const float4*)&g_lds[(sbase + i) * 128 + d0];
                const float4 gb = *(const float4*)&g_lds[(sbase + i) * 128 + d0 + 4];
                t_acc[i] += ga.x * waA[0] + ga.y * waA[1] + ga.z * waA[2] + ga.w * waA[3]
                          + gb.x * waA[4] + gb.y * waA[5] + gb.z * waA[6] + gb.w * waA[7];
                l_acc[i] += ga.x * wpA[0] + ga.y * wpA[1] + ga.z * wpA[2] + ga.w * wpA[3]
                          + gb.x * wpA[4] + gb.y * wpA[5] + gb.z * wpA[6] + gb.w * wpA[7];
            }
            const int nxt = (d0 + 16) & 127;   // wraps to 0 on last iter (harmless)
            #pragma unroll
            for (int j = 0; j < 8; ++j) {      // prefetch rows nxt..nxt+7
                waA[j] = Wa[(nxt + j) * 128 + c];
                wpA[j] = Wp[(nxt + j) * 128 + c];
            }
            #pragma unroll
            for (int i = 0; i < 4; ++i) {      // FMA rows d0+8..d0+15 (buffer B)
                const float4 ga = *(const float4*)&g_lds[(sbase + i) * 128 + d0 + 8];
                const float4 gb = *(const float4*)&g_lds[(sbase + i) * 128 + d0 + 12];
                t_acc[i] += ga.x * waB[0] + ga.y * waB[1] + ga.z * waB[2] + ga.w * waB[3]
                          + gb.x * waB[4] + gb.y * waB[5] + gb.z * waB[6] + gb.w * waB[7];
                l_acc[i] += ga.x * wpB[0] + ga.y * wpB[1] + ga.z * wpB[2] + ga.w * wpB[3]
                          + gb.x * wpB[4] + gb.y * wpB[5] + gb.z * wpB[6] + gb.w * wpB[7];
            }
        }
        #pragma unroll
        for (int i = 0; i < 4; ++i) {
            t_lds[(sbase + i) * 128 + c]     = t_acc[i];
            logit_lds[(sbase + i) * 132 + c] = l_acc[i];
        }
    }
    __syncthreads();

    // ---------- Phase D: per-wave {logit stats + scores + attn} ----------
    {
        // logit softmax stats, batched over the wave's 2 samples
        const float2 e0 = *(const float2*)&logit_lds[s0 * 132 + 2 * lane];
        const float2 e1 = *(const float2*)&logit_lds[(s0 + 1) * 132 + 2 * lane];
        float m0 = fmaxf(e0.x, e0.y), m1 = fmaxf(e1.x, e1.y);
        #pragma unroll
        for (int off = 32; off > 0; off >>= 1) {
            m0 = fmaxf(m0, __shfl_xor(m0, off, 64));
            m1 = fmaxf(m1, __shfl_xor(m1, off, 64));
        }
        float z0 = __expf(e0.x - m0) + __expf(e0.y - m0);
        float z1 = __expf(e1.x - m1) + __expf(e1.y - m1);
        #pragma unroll
        for (int off = 32; off > 0; off >>= 1) {
            z0 += __shfl_xor(z0, off, 64);
            z1 += __shfl_xor(z1, off, 64);
        }
        if (lane == 0) {
            stat_m[s0]     = m0;  stat_iz[s0]     = 1.f / z0;
            stat_m[s0 + 1] = m1;  stat_iz[s0 + 1] = 1.f / z1;
        }

        // scores: R already in registers (rA/rB), zero VMEM here
        float scA[9], scB[9];
        {
            const float2 tA = *(const float2*)&t_lds[s0 * 128 + 2 * lane];
            const float2 tB = *(const float2*)&t_lds[(s0 + 1) * 128 + 2 * lane];
            const float2 gA = *(const float2*)&g_lds[s0 * 128 + 2 * lane];
            const float2 gB = *(const float2*)&g_lds[(s0 + 1) * 128 + 2 * lane];
            scA[0] = tA.x * gA.x + tA.y * gA.y;
            scB[0] = tB.x * gB.x + tB.y * gB.y;
            #pragma unroll
            for (int m = 1; m < 9; ++m) {
                scA[m] = tA.x * rA[m - 1].x + tA.y * rA[m - 1].y;
                scB[m] = tB.x * rB[m - 1].x + tB.y * rB[m - 1].y;
            }
        }
        #pragma unroll
        for (int off = 32; off > 0; off >>= 1) {
            #pragma unroll
            for (int m = 0; m < 9; ++m) {
                scA[m] += __shfl_xor(scA[m], off, 64);
                scB[m] += __shfl_xor(scB[m], off, 64);
            }
        }
        // softmax over 9 (redundant per lane; static indices only)
        float mxA = scA[0], mxB = scB[0];
        #pragma unroll
        for (int m = 1; m < 9; ++m) { mxA = fmaxf(mxA, scA[m]); mxB = fmaxf(mxB, scB[m]); }
        float eA[9], eB[9], sA = 0.f, sB = 0.f;
        #pragma unroll
        for (int m = 0; m < 9; ++m) {
            eA[m] = __expf(scA[m] - mxA); sA += eA[m];
            eB[m] = __expf(scB[m] - mxB); sB += eB[m];
        }
        const float iA = 1.f / sA, iB = 1.f / sB;
        if (lane == 0) {
            #pragma unroll
            for (int m = 0; m < 8; ++m) {     // attn[8] only feeds normalization
                attn_lds[s0 * 8 + m]       = eA[m] * iA;
                attn_lds[(s0 + 1) * 8 + m] = eB[m] * iB;
            }
        }
    }
    __syncthreads();

    // ---------- Phase E: epilogue ----------
    #pragma unroll
    for (int i = 0; i < 4; ++i) {
        const int s = sbase + i;
        const float gl = __expf(l_acc[i] - stat_m[s]) * stat_iz[s];
        float val = attn_lds[s * 8 + 0] * gl;
        #pragma unroll
        for (int k = 0; k < 8; ++k)
            val += (lab_lds[s * 8 + k] == c) ? attn_lds[s * 8 + k] : 0.f;
        out[(size_t)(b0 + s) * 128 + c] = val;
    }
}

extern "C" void kernel_launch(void* const* d_in, const int* in_sizes, int n_in,
                              void* d_out, int out_size, void* d_ws, size_t ws_size,
                              hipStream_t stream) {
    const float* G      = (const float*)d_in[0];
    const float* R      = (const float*)d_in[1];
    const float* Wa     = (const float*)d_in[2];
    const float* Wp     = (const float*)d_in[3];
    const float* bpred  = (const float*)d_in[4];
    const int*   labels = (const int*)d_in[5];
    float*       o      = (float*)d_out;

    const int B = in_sizes[0] / 128;   // 16384
    dim3 grid(B / SB), block(THREADS);
    hipLaunchKernelGGL(graph_retrieval_fused, grid, block, 0, stream,
                       G, R, Wa, Wp, bpred, labels, o);
}

// Round 12
// 120.116 us; speedup vs baseline: 1.1573x; 1.1319x over previous
//
#include <hip/hip_runtime.h>

// GraphRetrieval fused kernel, MI355X (gfx950). Round 6: MFMA dual-GEMM.
// B=16384, K=8, D=128, C=128. All fp32; labels int32.
//
//   logits = g@W_pred + b_pred -> softmax(C) -> g_label
//   t      = g@W_adapter
//   scores[m] = t . concat(g, retr)[m], m=0..8 -> softmax -> attn
//   out[c] = attn[0]*g_label[c] + sum_k attn[k]*[labels[k]==c]   (k=0..7)
//
// Rounds 2-5 measured 53-57us, issue-bound: dual GEMM = 1024 VALU FMA +
// 128 ds_read_b128 per thread. Round 6 replaces it with split-bf16 MFMA
// (3x mfma_f32_16x16x32_bf16: AhBh + AlBh + AhBl; residual ~2^-16) so the
// score softmax keeps fp32-grade inputs. W is packed to fragment layout
// once per launch (prep kernel -> d_ws, 128 KB).

#define SB      16
#define THREADS 256

typedef __attribute__((ext_vector_type(8))) short bfrag_t;  // 8 bf16 (4 VGPR)
typedef __attribute__((ext_vector_type(4))) float facc_t;   // 4 f32 acc

__device__ __forceinline__ unsigned short bf16_hi_trunc(float f) {
    return (unsigned short)(__builtin_bit_cast(unsigned int, f) >> 16);
}
__device__ __forceinline__ float bf16_up(unsigned short h) {
    return __builtin_bit_cast(float, ((unsigned int)h) << 16);
}

// ---- prep: pack [Wa|Wp] (fp32 [128][128] each) into split-bf16 fragment
// layout.  chunk t in [0,4096): nt=t>>8, kk=(t>>6)&3, lane=t&63.
// lane holds col nt*16+(lane&15), k = kk*32+(lane>>4)*8 + 0..7 (16B).
__global__ __launch_bounds__(256)
void pack_w_kernel(const float* __restrict__ Wa, const float* __restrict__ Wp,
                   unsigned short* __restrict__ w_hi, unsigned short* __restrict__ w_lo) {
    const int t    = blockIdx.x * 256 + threadIdx.x;
    const int nt   = t >> 8;
    const int kk   = (t >> 6) & 3;
    const int lane = t & 63;
    const int n    = nt * 16 + (lane & 15);
    const int kb   = kk * 32 + (lane >> 4) * 8;
    const float* W = (n < 128) ? Wa : Wp;
    const int col  = n & 127;
    unsigned int h[4], l[4];
    #pragma unroll
    for (int i = 0; i < 4; ++i) {
        const float v0 = W[(kb + 2 * i) * 128 + col];
        const float v1 = W[(kb + 2 * i + 1) * 128 + col];
        const unsigned short h0 = bf16_hi_trunc(v0), h1 = bf16_hi_trunc(v1);
        const unsigned short l0 = bf16_hi_trunc(v0 - bf16_up(h0));
        const unsigned short l1 = bf16_hi_trunc(v1 - bf16_up(h1));
        h[i] = (unsigned int)h0 | ((unsigned int)h1 << 16);
        l[i] = (unsigned int)l0 | ((unsigned int)l1 << 16);
    }
    ((uint4*)w_hi)[t] = make_uint4(h[0], h[1], h[2], h[3]);
    ((uint4*)w_lo)[t] = make_uint4(l[0], l[1], l[2], l[3]);
}

__global__ __launch_bounds__(THREADS, 4)
void graph_retrieval_fused(const float* __restrict__ G,      // [B,128]
                           const float* __restrict__ R,      // [B,8,128]
                           const unsigned short* __restrict__ w_hi,
                           const unsigned short* __restrict__ w_lo,
                           const float* __restrict__ bp,     // [128]
                           const int*   __restrict__ labels, // [B,8]
                           float* __restrict__ out)          // [B,128]
{
    __shared__ float g_lds[SB * 132];       // padded pitch 132 (bank spread)
    __shared__ float t_lds[SB * 132];
    __shared__ float logit_lds[SB * 132];
    __shared__ float attn_lds[SB * 8];
    __shared__ float stat_m[SB], stat_iz[SB];
    __shared__ int   lab_lds[SB * 8];

    const int tid  = threadIdx.x;
    const int b0   = blockIdx.x * SB;
    const int wv   = tid >> 6;
    const int lane = tid & 63;

    // ---------- Phase A: stage g (padded) + labels ----------
    {
        const float4* Gv = (const float4*)(G + (size_t)b0 * 128);
        #pragma unroll
        for (int rpt = 0; rpt < 2; ++rpt) {
            const int idx = rpt * 256 + tid;          // 0..511 over [16][32] f4
            const int row = idx >> 5, j = idx & 31;
            ((float4*)g_lds)[row * 33 + j] = Gv[idx]; // pitch 33 f4 = 132 f
        }
        if (tid < SB * 8) lab_lds[tid] = labels[b0 * 8 + tid];
    }
    __syncthreads();

    // ---------- Phase B: dual GEMM via split-bf16 MFMA ----------
    {
        // A fragments: row = lane&15 (sample), k = (lane>>4)*8 + j + 32*kk
        const int arow = lane & 15;
        const int kch  = lane >> 4;
        bfrag_t a_hi[4], a_lo[4];
        #pragma unroll
        for (int kk = 0; kk < 4; ++kk) {
            const float* src = &g_lds[arow * 132 + kk * 32 + kch * 8];
            const float4 f0 = *(const float4*)src;
            const float4 f1 = *(const float4*)(src + 4);
            const float f[8] = {f0.x, f0.y, f0.z, f0.w, f1.x, f1.y, f1.z, f1.w};
            #pragma unroll
            for (int i = 0; i < 8; ++i) {
                const unsigned short hb = bf16_hi_trunc(f[i]);
                a_hi[kk][i] = (short)hb;
                a_lo[kk][i] = (short)bf16_hi_trunc(f[i] - bf16_up(hb));
            }
        }

        facc_t acc[4] = {{0.f,0.f,0.f,0.f},{0.f,0.f,0.f,0.f},
                         {0.f,0.f,0.f,0.f},{0.f,0.f,0.f,0.f}};
        #pragma unroll
        for (int p = 0; p < 4; ++p) {
            const int nt = wv * 4 + p;
            #pragma unroll
            for (int kk = 0; kk < 4; ++kk) {
                const int idx = (nt * 4 + kk) * 64 + lane;
                const bfrag_t bh = ((const bfrag_t*)w_hi)[idx];
                const bfrag_t bl = ((const bfrag_t*)w_lo)[idx];
                acc[p] = __builtin_amdgcn_mfma_f32_16x16x32_bf16(a_hi[kk], bh, acc[p], 0, 0, 0);
                acc[p] = __builtin_amdgcn_mfma_f32_16x16x32_bf16(a_lo[kk], bh, acc[p], 0, 0, 0);
                acc[p] = __builtin_amdgcn_mfma_f32_16x16x32_bf16(a_hi[kk], bl, acc[p], 0, 0, 0);
            }
        }

        // write back: C/D layout col=lane&15, row=(lane>>4)*4+j  [m89]
        const int crow = (lane >> 4) * 4;
        #pragma unroll
        for (int p = 0; p < 4; ++p) {
            const int coll = p * 16 + (lane & 15);     // within wave's 64 cols
            if (wv < 2) {                              // t = g@Wa
                const int c_t = wv * 64 + coll;
                #pragma unroll
                for (int j = 0; j < 4; ++j)
                    t_lds[(crow + j) * 132 + c_t] = acc[p][j];
            } else {                                   // logits = g@Wp + b
                const int c_l = (wv - 2) * 64 + coll;
                const float bias = bp[c_l];
                #pragma unroll
                for (int j = 0; j < 4; ++j)
                    logit_lds[(crow + j) * 132 + c_l] = acc[p][j] + bias;
            }
        }
    }
    __syncthreads();

    // ---------- Phase C/D: per-wave {logit stats + scores + attn}, 4 samples ----------
    {
        const int s0 = wv * 4;

        // logit softmax stats (batched over 4 samples)
        float mx[4], zs[4];
        float2 ev[4];
        #pragma unroll
        for (int q = 0; q < 4; ++q) {
            ev[q] = *(const float2*)&logit_lds[(s0 + q) * 132 + 2 * lane];
            mx[q] = fmaxf(ev[q].x, ev[q].y);
        }
        #pragma unroll
        for (int off = 32; off > 0; off >>= 1)
            #pragma unroll
            for (int q = 0; q < 4; ++q)
                mx[q] = fmaxf(mx[q], __shfl_xor(mx[q], off, 64));
        #pragma unroll
        for (int q = 0; q < 4; ++q)
            zs[q] = __expf(ev[q].x - mx[q]) + __expf(ev[q].y - mx[q]);
        #pragma unroll
        for (int off = 32; off > 0; off >>= 1)
            #pragma unroll
            for (int q = 0; q < 4; ++q)
                zs[q] += __shfl_xor(zs[q], off, 64);
        if (lane == 0) {
            #pragma unroll
            for (int q = 0; q < 4; ++q) {
                stat_m[s0 + q]  = mx[q];
                stat_iz[s0 + q] = 1.f / zs[q];
            }
        }

        // scores (fp32; t from MFMA accumulators via LDS)
        float sc[4][9];
        #pragma unroll
        for (int q = 0; q < 4; ++q) {
            const int s = s0 + q;
            const float2 t2 = *(const float2*)&t_lds[s * 132 + 2 * lane];
            const float2 g2 = *(const float2*)&g_lds[s * 132 + 2 * lane];
            sc[q][0] = t2.x * g2.x + t2.y * g2.y;
            const float2* Rr = (const float2*)(R + (size_t)(b0 + s) * 1024);
            #pragma unroll
            for (int m = 1; m < 9; ++m) {
                const float2 r2 = Rr[(m - 1) * 64 + lane];   // 512B/row coalesced
                sc[q][m] = t2.x * r2.x + t2.y * r2.y;
            }
        }
        #pragma unroll
        for (int off = 32; off > 0; off >>= 1)
            #pragma unroll
            for (int q = 0; q < 4; ++q)
                #pragma unroll
                for (int m = 0; m < 9; ++m)
                    sc[q][m] += __shfl_xor(sc[q][m], off, 64);

        #pragma unroll
        for (int q = 0; q < 4; ++q) {
            float m9 = sc[q][0];
            #pragma unroll
            for (int m = 1; m < 9; ++m) m9 = fmaxf(m9, sc[q][m]);
            float e[9], sum = 0.f;
            #pragma unroll
            for (int m = 0; m < 9; ++m) { e[m] = __expf(sc[q][m] - m9); sum += e[m]; }
            const float inv = 1.f / sum;
            if (lane == 0) {
                #pragma unroll
                for (int m = 0; m < 8; ++m)          // attn[8] only normalizes
                    attn_lds[(s0 + q) * 8 + m] = e[m] * inv;
            }
        }
    }
    __syncthreads();

    // ---------- Phase E: epilogue ----------
    {
        const int c  = tid & 127;
        const int hh = tid >> 7;
        #pragma unroll
        for (int i = 0; i < 8; ++i) {
            const int s = hh * 8 + i;
            const float lg = logit_lds[s * 132 + c];
            const float gl = __expf(lg - stat_m[s]) * stat_iz[s];
            const int4   la = *(const int4*)&lab_lds[s * 8];
            const int4   lb = *(const int4*)&lab_lds[s * 8 + 4];
            const float4 a0 = *(const float4*)&attn_lds[s * 8];
            const float4 a1 = *(const float4*)&attn_lds[s * 8 + 4];
            float val = a0.x * gl;
            val += (la.x == c) ? a0.x : 0.f;
            val += (la.y == c) ? a0.y : 0.f;
            val += (la.z == c) ? a0.z : 0.f;
            val += (la.w == c) ? a0.w : 0.f;
            val += (lb.x == c) ? a1.x : 0.f;
            val += (lb.y == c) ? a1.y : 0.f;
            val += (lb.z == c) ? a1.z : 0.f;
            val += (lb.w == c) ? a1.w : 0.f;
            out[(size_t)(b0 + s) * 128 + c] = val;
        }
    }
}

extern "C" void kernel_launch(void* const* d_in, const int* in_sizes, int n_in,
                              void* d_out, int out_size, void* d_ws, size_t ws_size,
                              hipStream_t stream) {
    const float* G      = (const float*)d_in[0];
    const float* R      = (const float*)d_in[1];
    const float* Wa     = (const float*)d_in[2];
    const float* Wp     = (const float*)d_in[3];
    const float* bpred  = (const float*)d_in[4];
    const int*   labels = (const int*)d_in[5];
    float*       o      = (float*)d_out;

    unsigned short* w_hi = (unsigned short*)d_ws;          // 64 KB
    unsigned short* w_lo = w_hi + 4096 * 8;                // next 64 KB

    hipLaunchKernelGGL(pack_w_kernel, dim3(16), dim3(256), 0, stream,
                       Wa, Wp, w_hi, w_lo);

    const int B = in_sizes[0] / 128;   // 16384
    hipLaunchKernelGGL(graph_retrieval_fused, dim3(B / SB), dim3(THREADS), 0, stream,
                       G, R, w_hi, w_lo, bpred, labels, o);
}